// Round 1
// baseline (5278.173 us; speedup 1.0000x reference)
//
#include <hip/hip_runtime.h>

#define NN 150000
#define NE 600000
#define NG 5000
#define H 128

typedef short bf16x8 __attribute__((ext_vector_type(8)));
typedef float f32x4 __attribute__((ext_vector_type(4)));

__device__ __forceinline__ short f2bf(float f) {
    unsigned u = __builtin_bit_cast(unsigned, f);
    u += 0x7fffu + ((u >> 16) & 1u);
    return (short)(u >> 16);
}

// h = x @ Wn + bn_b   [NN,6]@[6,H]
__global__ __launch_bounds__(256) void encoder_k(const float* __restrict__ x,
                                                 const float* __restrict__ Wn,
                                                 const float* __restrict__ bn_b,
                                                 float* __restrict__ h) {
    int t = blockIdx.x * 256 + threadIdx.x;   // over NN*H
    int i = t >> 7, j = t & 127;
    float acc = bn_b[j];
#pragma unroll
    for (int k = 0; k < 6; k++) acc += x[i * 6 + k] * Wn[k * H + j];
    h[t] = acc;
}

// agg = (1+eps[l]) * h ; block 0 zeroes stats
__global__ __launch_bounds__(256) void init_agg_k(const float* __restrict__ h,
                                                  float* __restrict__ agg,
                                                  const float* __restrict__ eps, int l,
                                                  float* __restrict__ stats) {
    if (blockIdx.x == 0) stats[threadIdx.x] = 0.f;
    int t = blockIdx.x * 256 + threadIdx.x;   // over NN*H/4
    float e = 1.f + eps[l];
    float4 v = ((const float4*)h)[t];
    v.x *= e; v.y *= e; v.z *= e; v.w *= e;
    ((float4*)agg)[t] = v;
}

// agg[dst] += h[src]  (thread = edge x float4-chunk)
__global__ __launch_bounds__(256) void scatter_k(const float* __restrict__ h,
                                                 const int* __restrict__ ei,
                                                 float* __restrict__ agg) {
    int t = blockIdx.x * 256 + threadIdx.x;   // NE*32
    int e = t >> 5, q = t & 31;
    int src = ei[e], dst = ei[NE + e];
    float4 v = *(const float4*)&h[(size_t)src * H + q * 4];
    float* d = &agg[(size_t)dst * H + q * 4];
    atomicAdd(d + 0, v.x);
    atomicAdd(d + 1, v.y);
    atomicAdd(d + 2, v.z);
    atomicAdd(d + 3, v.w);
}

// C[M,128] = op(A[M,128] @ W[128,128] + bias), bf16 MFMA, fp32 accum
template <bool RELU>
__global__ __launch_bounds__(256) void gemm128(const float* __restrict__ A,
                                               const float* __restrict__ W, int ldW,
                                               const float* __restrict__ bias,
                                               float* __restrict__ C, int ldC, int M) {
    __shared__ short Wlds[128 * 136];   // W^T, padded: Wlds[n*136+k]
    int tid = threadIdx.x;
    for (int idx = tid; idx < 128 * 128; idx += 256) {
        int k = idx >> 7, n = idx & 127;
        Wlds[n * 136 + k] = f2bf(W[k * ldW + n]);
    }
    __syncthreads();

    int w = tid >> 6, lane = tid & 63;
    int quad = lane >> 4, lr = lane & 15;
    int rowA = blockIdx.x * 64 + w * 16 + lr;
    bool rowOK = rowA < M;
    const float* ap = A + (size_t)rowA * 128 + quad * 8;

    f32x4 acc[8];
#pragma unroll
    for (int c = 0; c < 8; c++) acc[c] = (f32x4){0.f, 0.f, 0.f, 0.f};

#pragma unroll
    for (int kk = 0; kk < 4; kk++) {
        bf16x8 af;
        if (rowOK) {
            float4 v0 = *(const float4*)(ap + kk * 32);
            float4 v1 = *(const float4*)(ap + kk * 32 + 4);
            af[0] = f2bf(v0.x); af[1] = f2bf(v0.y); af[2] = f2bf(v0.z); af[3] = f2bf(v0.w);
            af[4] = f2bf(v1.x); af[5] = f2bf(v1.y); af[6] = f2bf(v1.z); af[7] = f2bf(v1.w);
        } else {
            af = (bf16x8){0, 0, 0, 0, 0, 0, 0, 0};
        }
#pragma unroll
        for (int c = 0; c < 8; c++) {
            bf16x8 bf = *(const bf16x8*)&Wlds[(c * 16 + lr) * 136 + kk * 32 + quad * 8];
            acc[c] = __builtin_amdgcn_mfma_f32_16x16x32_bf16(af, bf, acc[c], 0, 0, 0);
        }
    }

    int r0 = blockIdx.x * 64 + w * 16 + quad * 4;
#pragma unroll
    for (int c = 0; c < 8; c++) {
        int col = c * 16 + lr;
        float bv = bias[col];
#pragma unroll
        for (int r = 0; r < 4; r++) {
            int row = r0 + r;
            if (row < M) {
                float v = acc[c][r] + bv;
                if (RELU) v = fmaxf(v, 0.f);
                C[(size_t)row * ldC + col] = v;
            }
        }
    }
}

// column sums & sumsq of m -> stats[0..127]=sum, [128..255]=sumsq
__global__ __launch_bounds__(256) void stats_k(const float* __restrict__ m,
                                               float* __restrict__ stats, int M) {
    int col = threadIdx.x & 127;
    int half = threadIdx.x >> 7;
    int rpb = (M + gridDim.x - 1) / gridDim.x;
    int r0 = blockIdx.x * rpb;
    int r1 = min(r0 + rpb, M);
    float s = 0.f, s2 = 0.f;
    for (int r = r0 + half; r < r1; r += 2) {
        float v = m[(size_t)r * H + col];
        s += v; s2 += v * v;
    }
    __shared__ float ls[256], ls2[256];
    ls[threadIdx.x] = s; ls2[threadIdx.x] = s2;
    __syncthreads();
    if (threadIdx.x < 128) {
        s = ls[threadIdx.x] + ls[threadIdx.x + 128];
        s2 = ls2[threadIdx.x] + ls2[threadIdx.x + 128];
        atomicAdd(&stats[col], s);
        atomicAdd(&stats[128 + col], s2);
    }
}

// coef[c]=gamma*istd, coef[128+c]=beta-mu*gamma*istd
__global__ __launch_bounds__(128) void finalize_stats_k(const float* __restrict__ stats,
                                                        const float* __restrict__ gamma,
                                                        const float* __restrict__ beta,
                                                        float* __restrict__ coef, float invN) {
    int c = threadIdx.x;
    float mu = stats[c] * invN;
    float var = stats[128 + c] * invN - mu * mu;
    float a = gamma[c] * rsqrtf(var + 1e-5f);
    coef[c] = a;
    coef[128 + c] = beta[c] - mu * a;
}

// h = relu(m*a + b) + h
__global__ __launch_bounds__(256) void bn_apply_k(const float* __restrict__ m,
                                                  const float* __restrict__ coef,
                                                  float* __restrict__ h) {
    int t = blockIdx.x * 256 + threadIdx.x;   // over NN*H/4
    int c4 = t & 31;
    float4 a = ((const float4*)coef)[c4];
    float4 b = ((const float4*)coef)[32 + c4];
    float4 mv = ((const float4*)m)[t];
    float4 hv = ((const float4*)h)[t];
    hv.x += fmaxf(mv.x * a.x + b.x, 0.f);
    hv.y += fmaxf(mv.y * a.y + b.y, 0.f);
    hv.z += fmaxf(mv.z * a.z + b.z, 0.f);
    hv.w += fmaxf(mv.w * a.w + b.w, 0.f);
    ((float4*)h)[t] = hv;
}

// psum[batch[i]] += h[i]; pcnt[batch[i]] += 1
__global__ __launch_bounds__(256) void pool_scatter_k(const float* __restrict__ h,
                                                      const int* __restrict__ batch,
                                                      float* __restrict__ psum,
                                                      float* __restrict__ pcnt) {
    int t = blockIdx.x * 256 + threadIdx.x;   // NN*32
    int i = t >> 5, q = t & 31;
    int g = batch[i];
    float4 v = *(const float4*)&h[(size_t)i * H + q * 4];
    float* d = &psum[(size_t)g * H + q * 4];
    atomicAdd(d + 0, v.x);
    atomicAdd(d + 1, v.y);
    atomicAdd(d + 2, v.z);
    atomicAdd(d + 3, v.w);
    if (q == 0) atomicAdd(&pcnt[g], 1.f);
}

// psum /= max(pcnt,1) in place
__global__ __launch_bounds__(256) void finalize_pool_k(float* __restrict__ psum,
                                                       const float* __restrict__ pcnt) {
    int t = blockIdx.x * 256 + threadIdx.x;   // NG*H
    int g = t >> 7;
    psum[t] = psum[t] / fmaxf(pcnt[g], 1.f);
}

extern "C" void kernel_launch(void* const* d_in, const int* in_sizes, int n_in,
                              void* d_out, int out_size, void* d_ws, size_t ws_size,
                              hipStream_t stream) {
    const float* x     = (const float*)d_in[0];
    const int*   ei    = (const int*)d_in[1];
    const int*   batch = (const int*)d_in[2];
    const float* Wn    = (const float*)d_in[3];
    const float* bn_b  = (const float*)d_in[4];
    const float* eps   = (const float*)d_in[5];
    const float* W1    = (const float*)d_in[6];
    const float* b1    = (const float*)d_in[7];
    const float* W2    = (const float*)d_in[8];
    const float* b2    = (const float*)d_in[9];
    const float* gamma = (const float*)d_in[10];
    const float* beta  = (const float*)d_in[11];
    const float* Wo1   = (const float*)d_in[12];
    const float* bo1   = (const float*)d_in[13];
    const float* Wo2   = (const float*)d_in[14];
    const float* bo2   = (const float*)d_in[15];
    float* out = (float*)d_out;

    float* ws    = (float*)d_ws;
    float* h     = ws;                       // 19,200,000
    float* bufA  = h + 19200000;             // 19,200,000 (agg / m2)
    float* bufB  = bufA + 19200000;          // 19,200,000 (t / t1)
    float* stats = bufB + 19200000;          // 256
    float* coef  = stats + 256;              // 256
    float* psum  = coef + 256;               // NG*H
    float* pcnt  = psum + NG * H;            // NG

    encoder_k<<<75000, 256, 0, stream>>>(x, Wn, bn_b, h);

    for (int l = 0; l < 4; l++) {
        init_agg_k<<<18750, 256, 0, stream>>>(h, bufA, eps, l, stats);
        scatter_k<<<75000, 256, 0, stream>>>(h, ei, bufA);
        gemm128<true><<<2344, 256, 0, stream>>>(bufA, W1 + l * 16384, 128, b1 + l * 128,
                                                bufB, 128, NN);
        gemm128<false><<<2344, 256, 0, stream>>>(bufB, W2 + l * 16384, 128, b2 + l * 128,
                                                 bufA, 128, NN);
        stats_k<<<512, 256, 0, stream>>>(bufA, stats, NN);
        finalize_stats_k<<<1, 128, 0, stream>>>(stats, gamma + l * 128, beta + l * 128,
                                                coef, 1.f / NN);
        bn_apply_k<<<18750, 256, 0, stream>>>(bufA, coef, h);
    }

    hipMemsetAsync(psum, 0, (NG * H + NG) * sizeof(float), stream);
    pool_scatter_k<<<18750, 256, 0, stream>>>(h, batch, psum, pcnt);
    finalize_pool_k<<<2500, 256, 0, stream>>>(psum, pcnt);

    gemm128<true><<<79, 256, 0, stream>>>(psum, Wo1, 128, bo1, bufB, 128, NG);
    gemm128<false><<<79, 256, 0, stream>>>(bufB, Wo2, 256, bo2, out, 256, NG);
    gemm128<false><<<79, 256, 0, stream>>>(bufB, Wo2 + 128, 256, bo2 + 128, out + 128, 256, NG);
}

// Round 4
// 1179.353 us; speedup vs baseline: 4.4755x; 4.4755x over previous
//
#include <hip/hip_runtime.h>

#define NN 150000
#define NE 600000
#define NG 5000
#define H 128
#define NOFF (NN + 1)
#define NBLK 147   // ceil(150001 / 1024)

typedef short bf16x8 __attribute__((ext_vector_type(8)));
typedef float f32x4 __attribute__((ext_vector_type(4)));

__device__ __forceinline__ short f2bf(float f) {
    unsigned u = __builtin_bit_cast(unsigned, f);
    u += 0x7fffu + ((u >> 16) & 1u);
    return (short)(u >> 16);
}

// h = x @ Wn + bn_b   [NN,6]@[6,H]
__global__ __launch_bounds__(256) void encoder_k(const float* __restrict__ x,
                                                 const float* __restrict__ Wn,
                                                 const float* __restrict__ bn_b,
                                                 float* __restrict__ h) {
    int t = blockIdx.x * 256 + threadIdx.x;   // over NN*H
    int i = t >> 7, j = t & 127;
    float acc = bn_b[j];
#pragma unroll
    for (int k = 0; k < 6; k++) acc += x[i * 6 + k] * Wn[k * H + j];
    h[t] = acc;
}

// ---------- CSR build: histogram -> exclusive scan -> fill ----------

__global__ __launch_bounds__(256) void hist_k(const int* __restrict__ ei,
                                              int* __restrict__ deg) {
    int e = blockIdx.x * 256 + threadIdx.x;
    if (e < NE) atomicAdd(&deg[ei[NE + e]], 1);
}

// block-local exclusive scan over chunks of 1024 (256 thr x 4)
__global__ __launch_bounds__(256) void scan1_k(const int* __restrict__ deg,
                                               int* __restrict__ part,
                                               int* __restrict__ bsum) {
    __shared__ int ls[256];
    int tid = threadIdx.x;
    int base = blockIdx.x * 1024 + tid * 4;
    int v[4], s = 0;
#pragma unroll
    for (int j = 0; j < 4; j++) {
        int idx = base + j;
        v[j] = (idx < NN) ? deg[idx] : 0;
        s += v[j];
    }
    ls[tid] = s;
    __syncthreads();
    for (int off = 1; off < 256; off <<= 1) {
        int t2 = (tid >= off) ? ls[tid - off] : 0;
        __syncthreads();
        if (tid >= off) ls[tid] += t2;
        __syncthreads();
    }
    int run = ls[tid] - s;   // exclusive prefix of this thread within block
#pragma unroll
    for (int j = 0; j < 4; j++) {
        int idx = base + j;
        if (idx < NOFF) part[idx] = run;
        run += v[j];
    }
    if (tid == 255) bsum[blockIdx.x] = ls[255];
}

__global__ __launch_bounds__(256) void scan2_k(int* __restrict__ bsum) {
    __shared__ int ls[256];
    int tid = threadIdx.x;
    int v = (tid < NBLK) ? bsum[tid] : 0;
    ls[tid] = v;
    __syncthreads();
    for (int off = 1; off < 256; off <<= 1) {
        int t2 = (tid >= off) ? ls[tid - off] : 0;
        __syncthreads();
        if (tid >= off) ls[tid] += t2;
        __syncthreads();
    }
    if (tid < NBLK) bsum[tid] = ls[tid] - v;   // exclusive
}

__global__ __launch_bounds__(256) void scan3_k(const int* __restrict__ part,
                                               const int* __restrict__ bsum,
                                               int* __restrict__ offsets,
                                               int* __restrict__ cursor) {
    int tid = threadIdx.x;
    int base = blockIdx.x * 1024 + tid * 4;
    int bs = bsum[blockIdx.x];
#pragma unroll
    for (int j = 0; j < 4; j++) {
        int idx = base + j;
        if (idx < NOFF) {
            int o = part[idx] + bs;
            offsets[idx] = o;
            if (idx < NN) cursor[idx] = o;
        }
    }
}

__global__ __launch_bounds__(256) void fill_k(const int* __restrict__ ei,
                                              int* __restrict__ cursor,
                                              int* __restrict__ adj) {
    int e = blockIdx.x * 256 + threadIdx.x;
    if (e < NE) {
        int p = atomicAdd(&cursor[ei[NE + e]], 1);
        if (p >= 0 && p < NE) adj[p] = ei[e];
    }
}

// ---------- per-layer gather: agg = (1+eps)*h + sum_{j->i} h[j] ----------
__global__ __launch_bounds__(256) void gather_k(const float* __restrict__ h,
                                                const int* __restrict__ offsets,
                                                const int* __restrict__ adj,
                                                const float* __restrict__ eps, int l,
                                                float* __restrict__ agg,
                                                float* __restrict__ stats) {
    if (blockIdx.x == 0) stats[threadIdx.x] = 0.f;
    int t = blockIdx.x * 256 + threadIdx.x;   // NN*32
    int i = t >> 5, q = t & 31;
    const float4* hp = (const float4*)h;
    float e = 1.f + eps[l];
    float4 acc = hp[(size_t)i * 32 + q];
    acc.x *= e; acc.y *= e; acc.z *= e; acc.w *= e;
    int s0 = offsets[i], s1 = offsets[i + 1];
    for (int k = s0; k < s1; k++) {
        int src = adj[k];
        float4 v = hp[(size_t)src * 32 + q];
        acc.x += v.x; acc.y += v.y; acc.z += v.z; acc.w += v.w;
    }
    ((float4*)agg)[(size_t)i * 32 + q] = acc;
}

// C[M,128] = op(A[M,128] @ W[128,128] + bias), bf16 MFMA, fp32 accum
template <bool RELU>
__global__ __launch_bounds__(256) void gemm128(const float* __restrict__ A,
                                               const float* __restrict__ W, int ldW,
                                               const float* __restrict__ bias,
                                               float* __restrict__ C, int ldC, int M) {
    __shared__ short Wlds[128 * 136];   // W^T, padded: Wlds[n*136+k]
    int tid = threadIdx.x;
    for (int idx = tid; idx < 128 * 128; idx += 256) {
        int k = idx >> 7, n = idx & 127;
        Wlds[n * 136 + k] = f2bf(W[k * ldW + n]);
    }
    __syncthreads();

    int w = tid >> 6, lane = tid & 63;
    int quad = lane >> 4, lr = lane & 15;
    int rowA = blockIdx.x * 64 + w * 16 + lr;
    bool rowOK = rowA < M;
    const float* ap = A + (size_t)rowA * 128 + quad * 8;

    f32x4 acc[8];
#pragma unroll
    for (int c = 0; c < 8; c++) acc[c] = (f32x4){0.f, 0.f, 0.f, 0.f};

#pragma unroll
    for (int kk = 0; kk < 4; kk++) {
        bf16x8 af;
        if (rowOK) {
            float4 v0 = *(const float4*)(ap + kk * 32);
            float4 v1 = *(const float4*)(ap + kk * 32 + 4);
            af[0] = f2bf(v0.x); af[1] = f2bf(v0.y); af[2] = f2bf(v0.z); af[3] = f2bf(v0.w);
            af[4] = f2bf(v1.x); af[5] = f2bf(v1.y); af[6] = f2bf(v1.z); af[7] = f2bf(v1.w);
        } else {
            af = (bf16x8){0, 0, 0, 0, 0, 0, 0, 0};
        }
#pragma unroll
        for (int c = 0; c < 8; c++) {
            bf16x8 bf = *(const bf16x8*)&Wlds[(c * 16 + lr) * 136 + kk * 32 + quad * 8];
            acc[c] = __builtin_amdgcn_mfma_f32_16x16x32_bf16(af, bf, acc[c], 0, 0, 0);
        }
    }

    int r0 = blockIdx.x * 64 + w * 16 + quad * 4;
#pragma unroll
    for (int c = 0; c < 8; c++) {
        int col = c * 16 + lr;
        float bv = bias[col];
#pragma unroll
        for (int r = 0; r < 4; r++) {
            int row = r0 + r;
            if (row < M) {
                float v = acc[c][r] + bv;
                if (RELU) v = fmaxf(v, 0.f);
                C[(size_t)row * ldC + col] = v;
            }
        }
    }
}

// column sums & sumsq of m -> stats[0..127]=sum, [128..255]=sumsq
__global__ __launch_bounds__(256) void stats_k(const float* __restrict__ m,
                                               float* __restrict__ stats, int M) {
    int col = threadIdx.x & 127;
    int half = threadIdx.x >> 7;
    int rpb = (M + gridDim.x - 1) / gridDim.x;
    int r0 = blockIdx.x * rpb;
    int r1 = min(r0 + rpb, M);
    float s = 0.f, s2 = 0.f;
    for (int r = r0 + half; r < r1; r += 2) {
        float v = m[(size_t)r * H + col];
        s += v; s2 += v * v;
    }
    __shared__ float ls[256], ls2[256];
    ls[threadIdx.x] = s; ls2[threadIdx.x] = s2;
    __syncthreads();
    if (threadIdx.x < 128) {
        s = ls[threadIdx.x] + ls[threadIdx.x + 128];
        s2 = ls2[threadIdx.x] + ls2[threadIdx.x + 128];
        atomicAdd(&stats[col], s);
        atomicAdd(&stats[128 + col], s2);
    }
}

// coef[c]=gamma*istd, coef[128+c]=beta-mu*gamma*istd
__global__ __launch_bounds__(128) void finalize_stats_k(const float* __restrict__ stats,
                                                        const float* __restrict__ gamma,
                                                        const float* __restrict__ beta,
                                                        float* __restrict__ coef, float invN) {
    int c = threadIdx.x;
    float mu = stats[c] * invN;
    float var = stats[128 + c] * invN - mu * mu;
    float a = gamma[c] * rsqrtf(var + 1e-5f);
    coef[c] = a;
    coef[128 + c] = beta[c] - mu * a;
}

// h = relu(m*a + b) + h
__global__ __launch_bounds__(256) void bn_apply_k(const float* __restrict__ m,
                                                  const float* __restrict__ coef,
                                                  float* __restrict__ h) {
    int t = blockIdx.x * 256 + threadIdx.x;   // over NN*H/4
    int c4 = t & 31;
    float4 a = ((const float4*)coef)[c4];
    float4 b = ((const float4*)coef)[32 + c4];
    float4 mv = ((const float4*)m)[t];
    float4 hv = ((const float4*)h)[t];
    hv.x += fmaxf(mv.x * a.x + b.x, 0.f);
    hv.y += fmaxf(mv.y * a.y + b.y, 0.f);
    hv.z += fmaxf(mv.z * a.z + b.z, 0.f);
    hv.w += fmaxf(mv.w * a.w + b.w, 0.f);
    ((float4*)h)[t] = hv;
}

// ---------- pooling (batch is sorted) ----------

__global__ __launch_bounds__(256) void gbound_k(const int* __restrict__ batch,
                                                int* __restrict__ gstart) {
    int i = blockIdx.x * 256 + threadIdx.x;
    if (i >= NN) return;
    int b = batch[i];
    int prev = (i == 0) ? -1 : batch[i - 1];
    for (int g = prev + 1; g <= b; g++) gstart[g] = i;
    if (i == NN - 1) {
        for (int g = b + 1; g <= NG; g++) gstart[g] = NN;
    }
}

// one block per graph: mean over its node rows
__global__ __launch_bounds__(128) void pool_k(const float* __restrict__ h,
                                              const int* __restrict__ gstart,
                                              float* __restrict__ pooled) {
    int g = blockIdx.x, col = threadIdx.x;
    int r0 = gstart[g], r1 = gstart[g + 1];
    float s = 0.f;
    for (int r = r0; r < r1; r++) s += h[(size_t)r * H + col];
    pooled[(size_t)g * H + col] = s / fmaxf((float)(r1 - r0), 1.f);
}

extern "C" void kernel_launch(void* const* d_in, const int* in_sizes, int n_in,
                              void* d_out, int out_size, void* d_ws, size_t ws_size,
                              hipStream_t stream) {
    const float* x     = (const float*)d_in[0];
    const int*   ei    = (const int*)d_in[1];
    const int*   batch = (const int*)d_in[2];
    const float* Wn    = (const float*)d_in[3];
    const float* bn_b  = (const float*)d_in[4];
    const float* eps   = (const float*)d_in[5];
    const float* W1    = (const float*)d_in[6];
    const float* b1    = (const float*)d_in[7];
    const float* W2    = (const float*)d_in[8];
    const float* b2    = (const float*)d_in[9];
    const float* gamma = (const float*)d_in[10];
    const float* beta  = (const float*)d_in[11];
    const float* Wo1   = (const float*)d_in[12];
    const float* bo1   = (const float*)d_in[13];
    const float* Wo2   = (const float*)d_in[14];
    const float* bo2   = (const float*)d_in[15];
    float* out = (float*)d_out;

    // ---- workspace layout (keep peak ~= R1's 233 MB footprint) ----
    float* ws    = (float*)d_ws;
    float* h     = ws;                       // 19,200,000 f
    float* bufA  = h + 19200000;             // 19,200,000 f (agg / m2)
    float* bufB  = bufA + 19200000;          // 19,200,000 f (t / t1)
    float* stats = bufB + 19200000;          // 256 f
    float* coef  = stats + 256;              // 256 f
    float* pooled= coef + 256;               // NG*H f
    // persistent int arrays (needed across all layers): ~3.0 MB
    int*   offsets= (int*)(pooled + NG * H); // NOFF
    int*   adj    = offsets + NOFF;          // NE
    int*   gstart = adj + NE;                // NG+1
    // transient CSR-build arrays overlaid in bufA (only used BEFORE layer 0's
    // gather_k writes bufA; all on the same stream so ordering is guaranteed)
    int*   deg    = (int*)bufA;              // NN
    int*   part   = deg + NN;                // NOFF
    int*   bsum   = part + NOFF;             // 256
    int*   cursor = bsum + 256;              // NN

    // CSR build (once; reused by all 4 layers)
    hipMemsetAsync(deg, 0, NN * sizeof(int), stream);
    hist_k<<<2344, 256, 0, stream>>>(ei, deg);
    scan1_k<<<NBLK, 256, 0, stream>>>(deg, part, bsum);
    scan2_k<<<1, 256, 0, stream>>>(bsum);
    scan3_k<<<NBLK, 256, 0, stream>>>(part, bsum, offsets, cursor);
    fill_k<<<2344, 256, 0, stream>>>(ei, cursor, adj);
    gbound_k<<<586, 256, 0, stream>>>(batch, gstart);

    encoder_k<<<75000, 256, 0, stream>>>(x, Wn, bn_b, h);

    for (int l = 0; l < 4; l++) {
        gather_k<<<18750, 256, 0, stream>>>(h, offsets, adj, eps, l, bufA, stats);
        gemm128<true><<<2344, 256, 0, stream>>>(bufA, W1 + l * 16384, 128, b1 + l * 128,
                                                bufB, 128, NN);
        gemm128<false><<<2344, 256, 0, stream>>>(bufB, W2 + l * 16384, 128, b2 + l * 128,
                                                 bufA, 128, NN);
        stats_k<<<512, 256, 0, stream>>>(bufA, stats, NN);
        finalize_stats_k<<<1, 128, 0, stream>>>(stats, gamma + l * 128, beta + l * 128,
                                                coef, 1.f / NN);
        bn_apply_k<<<18750, 256, 0, stream>>>(bufA, coef, h);
    }

    pool_k<<<NG, 128, 0, stream>>>(h, gstart, pooled);

    gemm128<true><<<79, 256, 0, stream>>>(pooled, Wo1, 128, bo1, bufB, 128, NG);
    gemm128<false><<<79, 256, 0, stream>>>(bufB, Wo2, 256, bo2, out, 256, NG);
    gemm128<false><<<79, 256, 0, stream>>>(bufB, Wo2 + 128, 256, bo2 + 128, out + 128, 256, NG);
}

// Round 6
// 982.759 us; speedup vs baseline: 5.3708x; 1.2000x over previous
//
#include <hip/hip_runtime.h>

#define NN 150000
#define NE 600000
#define NG 5000
#define H 128
#define NOFF (NN + 1)
#define NBLK 147   // ceil(150001 / 1024)
#define NSPLIT 64  // stats_part split factor

typedef short bf16x8 __attribute__((ext_vector_type(8)));
typedef float f32x4 __attribute__((ext_vector_type(4)));

__device__ __forceinline__ unsigned short f2bf(float f) {
    unsigned u = __builtin_bit_cast(unsigned, f);
    u += 0x7fffu + ((u >> 16) & 1u);
    return (unsigned short)(u >> 16);
}
__device__ __forceinline__ float bf2f(unsigned short u) {
    return __builtin_bit_cast(float, (unsigned)u << 16);
}

// h = bf16(x @ Wn + bn_b)   [NN,6]@[6,H]
__global__ __launch_bounds__(256) void encoder_k(const float* __restrict__ x,
                                                 const float* __restrict__ Wn,
                                                 const float* __restrict__ bn_b,
                                                 unsigned short* __restrict__ h) {
    int t = blockIdx.x * 256 + threadIdx.x;   // over NN*H
    int i = t >> 7, j = t & 127;
    float acc = bn_b[j];
#pragma unroll
    for (int k = 0; k < 6; k++) acc += x[i * 6 + k] * Wn[k * H + j];
    h[t] = f2bf(acc);
}

// ---------- CSR build: histogram -> exclusive scan -> fill ----------

__global__ __launch_bounds__(256) void hist_k(const int* __restrict__ ei,
                                              int* __restrict__ deg) {
    int e = blockIdx.x * 256 + threadIdx.x;
    if (e < NE) atomicAdd(&deg[ei[NE + e]], 1);
}

__global__ __launch_bounds__(256) void scan1_k(const int* __restrict__ deg,
                                               int* __restrict__ part,
                                               int* __restrict__ bsum) {
    __shared__ int ls[256];
    int tid = threadIdx.x;
    int base = blockIdx.x * 1024 + tid * 4;
    int v[4], s = 0;
#pragma unroll
    for (int j = 0; j < 4; j++) {
        int idx = base + j;
        v[j] = (idx < NN) ? deg[idx] : 0;
        s += v[j];
    }
    ls[tid] = s;
    __syncthreads();
    for (int off = 1; off < 256; off <<= 1) {
        int t2 = (tid >= off) ? ls[tid - off] : 0;
        __syncthreads();
        if (tid >= off) ls[tid] += t2;
        __syncthreads();
    }
    int run = ls[tid] - s;
#pragma unroll
    for (int j = 0; j < 4; j++) {
        int idx = base + j;
        if (idx < NOFF) part[idx] = run;
        run += v[j];
    }
    if (tid == 255) bsum[blockIdx.x] = ls[255];
}

__global__ __launch_bounds__(256) void scan2_k(int* __restrict__ bsum) {
    __shared__ int ls[256];
    int tid = threadIdx.x;
    int v = (tid < NBLK) ? bsum[tid] : 0;
    ls[tid] = v;
    __syncthreads();
    for (int off = 1; off < 256; off <<= 1) {
        int t2 = (tid >= off) ? ls[tid - off] : 0;
        __syncthreads();
        if (tid >= off) ls[tid] += t2;
        __syncthreads();
    }
    if (tid < NBLK) bsum[tid] = ls[tid] - v;
}

__global__ __launch_bounds__(256) void scan3_k(const int* __restrict__ part,
                                               const int* __restrict__ bsum,
                                               int* __restrict__ offsets,
                                               int* __restrict__ cursor) {
    int tid = threadIdx.x;
    int base = blockIdx.x * 1024 + tid * 4;
    int bs = bsum[blockIdx.x];
#pragma unroll
    for (int j = 0; j < 4; j++) {
        int idx = base + j;
        if (idx < NOFF) {
            int o = part[idx] + bs;
            offsets[idx] = o;
            if (idx < NN) cursor[idx] = o;
        }
    }
}

__global__ __launch_bounds__(256) void fill_k(const int* __restrict__ ei,
                                              int* __restrict__ cursor,
                                              int* __restrict__ adj) {
    int e = blockIdx.x * 256 + threadIdx.x;
    if (e < NE) {
        int p = atomicAdd(&cursor[ei[NE + e]], 1);
        if (p >= 0 && p < NE) adj[p] = ei[e];
    }
}

// ---------- gather: agg = bf16((1+eps)*h + sum_{j->i} h[j]), fp32 accum ----------
__global__ __launch_bounds__(256) void gather_k(const unsigned short* __restrict__ h,
                                                const int* __restrict__ offsets,
                                                const int* __restrict__ adj,
                                                const float* __restrict__ eps, int l,
                                                unsigned short* __restrict__ agg,
                                                float* __restrict__ stats_part) {
    if (blockIdx.x < NSPLIT) stats_part[blockIdx.x * 256 + threadIdx.x] = 0.f;
    int t = blockIdx.x * 256 + threadIdx.x;   // NN*32, 4 cols per thread
    int i = t >> 5, q = t & 31;
    const ushort4* hp = (const ushort4*)h;
    float e = 1.f + eps[l];
    ushort4 sv = hp[(size_t)i * 32 + q];
    float a0 = bf2f(sv.x) * e, a1 = bf2f(sv.y) * e, a2 = bf2f(sv.z) * e, a3 = bf2f(sv.w) * e;
    int s0 = offsets[i], s1 = offsets[i + 1];
    for (int k = s0; k < s1; k++) {
        int src = adj[k];
        ushort4 v = hp[(size_t)src * 32 + q];
        a0 += bf2f(v.x); a1 += bf2f(v.y); a2 += bf2f(v.z); a3 += bf2f(v.w);
    }
    ushort4 o;
    o.x = f2bf(a0); o.y = f2bf(a1); o.z = f2bf(a2); o.w = f2bf(a3);
    ((ushort4*)agg)[(size_t)i * 32 + q] = o;
}

// C[M,128] = op(bf16 A[M,128] @ W[128,128] + bias); optional bf16 out, fused BN stats
template <bool RELU, bool OBF16, bool STATS>
__global__ __launch_bounds__(256) void gemm128b(const unsigned short* __restrict__ A,
                                                const float* __restrict__ W, int ldW,
                                                const float* __restrict__ bias,
                                                void* __restrict__ Cv, int ldC, int M,
                                                float* __restrict__ stats_part) {
    __shared__ short Wlds[128 * 136];   // W^T, padded: Wlds[n*136+k]
    __shared__ float sst[256];
    int tid = threadIdx.x;
    for (int idx = tid; idx < 128 * 128; idx += 256) {
        int k = idx >> 7, n = idx & 127;
        Wlds[n * 136 + k] = (short)f2bf(W[k * ldW + n]);
    }
    if (STATS) sst[tid] = 0.f;
    __syncthreads();

    int w = tid >> 6, lane = tid & 63;
    int quad = lane >> 4, lr = lane & 15;
    int rowA = blockIdx.x * 64 + w * 16 + lr;
    bool rowOK = rowA < M;
    const unsigned short* ap = A + (size_t)rowA * 128 + quad * 8;

    f32x4 acc[8];
#pragma unroll
    for (int c = 0; c < 8; c++) acc[c] = (f32x4){0.f, 0.f, 0.f, 0.f};

#pragma unroll
    for (int kk = 0; kk < 4; kk++) {
        bf16x8 af = rowOK ? *(const bf16x8*)(ap + kk * 32)
                          : (bf16x8){0, 0, 0, 0, 0, 0, 0, 0};
#pragma unroll
        for (int c = 0; c < 8; c++) {
            bf16x8 bf = *(const bf16x8*)&Wlds[(c * 16 + lr) * 136 + kk * 32 + quad * 8];
            acc[c] = __builtin_amdgcn_mfma_f32_16x16x32_bf16(af, bf, acc[c], 0, 0, 0);
        }
    }

    int r0 = blockIdx.x * 64 + w * 16 + quad * 4;
#pragma unroll
    for (int c = 0; c < 8; c++) {
        int col = c * 16 + lr;
        float bv = bias[col];
        float ls = 0.f, ls2 = 0.f;
#pragma unroll
        for (int r = 0; r < 4; r++) {
            int row = r0 + r;
            if (row < M) {
                float v = acc[c][r] + bv;
                if (RELU) v = fmaxf(v, 0.f);
                if (OBF16)
                    ((unsigned short*)Cv)[(size_t)row * ldC + col] = f2bf(v);
                else
                    ((float*)Cv)[(size_t)row * ldC + col] = v;
                if (STATS) { ls += v; ls2 += v * v; }
            }
        }
        if (STATS) {
            atomicAdd(&sst[col], ls);
            atomicAdd(&sst[128 + col], ls2);
        }
    }
    if (STATS) {
        __syncthreads();
        atomicAdd(&stats_part[(blockIdx.x & (NSPLIT - 1)) * 256 + tid], sst[tid]);
    }
}

// reduce stats_part -> coef[c]=gamma*istd, coef[128+c]=beta-mu*gamma*istd
__global__ __launch_bounds__(256) void finalize_stats_k(const float* __restrict__ stats_part,
                                                        const float* __restrict__ gamma,
                                                        const float* __restrict__ beta,
                                                        float* __restrict__ coef, float invN) {
    __shared__ float ls[256];
    int t = threadIdx.x;
    float s = 0.f;
    for (int p = 0; p < NSPLIT; p++) s += stats_part[p * 256 + t];
    ls[t] = s;
    __syncthreads();
    if (t < 128) {
        float mu = ls[t] * invN;
        float var = ls[128 + t] * invN - mu * mu;
        float a = gamma[t] * rsqrtf(var + 1e-5f);
        coef[t] = a;
        coef[128 + t] = beta[t] - mu * a;
    }
}

// h = bf16(relu(m*a + b) + h)
__global__ __launch_bounds__(256) void bn_apply_k(const float* __restrict__ m,
                                                  const float* __restrict__ coef,
                                                  unsigned short* __restrict__ h) {
    int t = blockIdx.x * 256 + threadIdx.x;   // NN*32, 4 cols per thread
    int c4 = t & 31;
    float4 a = ((const float4*)coef)[c4];
    float4 b = ((const float4*)coef)[32 + c4];
    float4 mv = ((const float4*)m)[t];
    ushort4 hv = ((const ushort4*)h)[t];
    float h0 = bf2f(hv.x) + fmaxf(mv.x * a.x + b.x, 0.f);
    float h1 = bf2f(hv.y) + fmaxf(mv.y * a.y + b.y, 0.f);
    float h2 = bf2f(hv.z) + fmaxf(mv.z * a.z + b.z, 0.f);
    float h3 = bf2f(hv.w) + fmaxf(mv.w * a.w + b.w, 0.f);
    ushort4 o;
    o.x = f2bf(h0); o.y = f2bf(h1); o.z = f2bf(h2); o.w = f2bf(h3);
    ((ushort4*)h)[t] = o;
}

// ---------- pooling (batch is sorted) ----------

__global__ __launch_bounds__(256) void gbound_k(const int* __restrict__ batch,
                                                int* __restrict__ gstart) {
    int i = blockIdx.x * 256 + threadIdx.x;
    if (i >= NN) return;
    int b = batch[i];
    int prev = (i == 0) ? -1 : batch[i - 1];
    for (int g = prev + 1; g <= b; g++) gstart[g] = i;
    if (i == NN - 1) {
        for (int g = b + 1; g <= NG; g++) gstart[g] = NN;
    }
}

// one block per graph: mean over its node rows -> bf16 pooled
__global__ __launch_bounds__(128) void pool_k(const unsigned short* __restrict__ h,
                                              const int* __restrict__ gstart,
                                              unsigned short* __restrict__ pooled) {
    int g = blockIdx.x, col = threadIdx.x;
    int r0 = gstart[g], r1 = gstart[g + 1];
    float s = 0.f;
    for (int r = r0; r < r1; r++) s += bf2f(h[(size_t)r * H + col]);
    pooled[(size_t)g * H + col] = f2bf(s / fmaxf((float)(r1 - r0), 1.f));
}

extern "C" void kernel_launch(void* const* d_in, const int* in_sizes, int n_in,
                              void* d_out, int out_size, void* d_ws, size_t ws_size,
                              hipStream_t stream) {
    const float* x     = (const float*)d_in[0];
    const int*   ei    = (const int*)d_in[1];
    const int*   batch = (const int*)d_in[2];
    const float* Wn    = (const float*)d_in[3];
    const float* bn_b  = (const float*)d_in[4];
    const float* eps   = (const float*)d_in[5];
    const float* W1    = (const float*)d_in[6];
    const float* b1    = (const float*)d_in[7];
    const float* W2    = (const float*)d_in[8];
    const float* b2    = (const float*)d_in[9];
    const float* gamma = (const float*)d_in[10];
    const float* beta  = (const float*)d_in[11];
    const float* Wo1   = (const float*)d_in[12];
    const float* bo1   = (const float*)d_in[13];
    const float* Wo2   = (const float*)d_in[14];
    const float* bo2   = (const float*)d_in[15];
    float* out = (float*)d_out;

    // ---- workspace: ~196 MB total ----
    unsigned short* h     = (unsigned short*)d_ws;                 // NN*H bf16
    float*          m     = (float*)(h + (size_t)NN * H);          // NN*H f32
    unsigned short* aggB  = (unsigned short*)(m + (size_t)NN * H); // NN*H bf16
    unsigned short* tB    = aggB + (size_t)NN * H;                 // NN*H bf16
    float* stats_part     = (float*)(tB + (size_t)NN * H);         // NSPLIT*256
    float* coef           = stats_part + NSPLIT * 256;             // 256
    unsigned short* pooledB = (unsigned short*)(coef + 256);       // NG*H bf16
    int* offsets = (int*)(pooledB + (size_t)NG * H);               // NOFF
    int* adj     = offsets + NOFF;                                 // NE
    int* gstart  = adj + NE;                                       // NG+1
    // transient CSR-build arrays overlaid in m (m is first written by layer-0
    // gemm2, strictly after the CSR build on the same stream)
    int* deg    = (int*)m;         // NN
    int* part   = deg + NN;        // NOFF
    int* bsum   = part + NOFF;     // 256
    int* cursor = bsum + 256;      // NN

    // CSR build (once; reused by all 4 layers)
    hipMemsetAsync(deg, 0, NN * sizeof(int), stream);
    hist_k<<<2344, 256, 0, stream>>>(ei, deg);
    scan1_k<<<NBLK, 256, 0, stream>>>(deg, part, bsum);
    scan2_k<<<1, 256, 0, stream>>>(bsum);
    scan3_k<<<NBLK, 256, 0, stream>>>(part, bsum, offsets, cursor);
    fill_k<<<2344, 256, 0, stream>>>(ei, cursor, adj);
    gbound_k<<<586, 256, 0, stream>>>(batch, gstart);

    encoder_k<<<75000, 256, 0, stream>>>(x, Wn, bn_b, h);

    for (int l = 0; l < 4; l++) {
        gather_k<<<18750, 256, 0, stream>>>(h, offsets, adj, eps, l, aggB, stats_part);
        gemm128b<true, true, false><<<2344, 256, 0, stream>>>(
            aggB, W1 + l * 16384, 128, b1 + l * 128, tB, 128, NN, nullptr);
        gemm128b<false, false, true><<<2344, 256, 0, stream>>>(
            tB, W2 + l * 16384, 128, b2 + l * 128, m, 128, NN, stats_part);
        finalize_stats_k<<<1, 256, 0, stream>>>(stats_part, gamma + l * 128,
                                                beta + l * 128, coef, 1.f / NN);
        bn_apply_k<<<18750, 256, 0, stream>>>(m, coef, h);
    }

    pool_k<<<NG, 128, 0, stream>>>(h, gstart, pooledB);

    gemm128b<true, true, false><<<79, 256, 0, stream>>>(
        pooledB, Wo1, 128, bo1, tB, 128, NG, nullptr);
    gemm128b<false, false, false><<<79, 256, 0, stream>>>(
        tB, Wo2, 256, bo2, out, 256, NG, nullptr);
    gemm128b<false, false, false><<<79, 256, 0, stream>>>(
        tB, Wo2 + 128, 256, bo2 + 128, out + 128, 256, NG, nullptr);
}

// Round 7
// 790.294 us; speedup vs baseline: 6.6787x; 1.2435x over previous
//
#include <hip/hip_runtime.h>

#define NN 150000
#define NE 600000
#define NG 5000
#define H 128
#define NOFF (NN + 1)
#define NBLK 147   // ceil(150001 / 1024)
#define NSPLIT 64  // stats_part split factor

typedef short bf16x8 __attribute__((ext_vector_type(8)));
typedef float f32x4 __attribute__((ext_vector_type(4)));

__device__ __forceinline__ unsigned short f2bf(float f) {
    unsigned u = __builtin_bit_cast(unsigned, f);
    u += 0x7fffu + ((u >> 16) & 1u);
    return (unsigned short)(u >> 16);
}
__device__ __forceinline__ float bf2f(unsigned short u) {
    return __builtin_bit_cast(float, (unsigned)u << 16);
}

// h = bf16(x @ Wn + bn_b)   [NN,6]@[6,H]
__global__ __launch_bounds__(256) void encoder_k(const float* __restrict__ x,
                                                 const float* __restrict__ Wn,
                                                 const float* __restrict__ bn_b,
                                                 unsigned short* __restrict__ h) {
    int t = blockIdx.x * 256 + threadIdx.x;   // over NN*H
    int i = t >> 7, j = t & 127;
    float acc = bn_b[j];
#pragma unroll
    for (int k = 0; k < 6; k++) acc += x[i * 6 + k] * Wn[k * H + j];
    h[t] = f2bf(acc);
}

// ---------- weight prepack: bf16, MFMA-fragment order ----------
// mat m in [0,11): 0-3 W1[l], 4-7 W2[l], 8 Wo1, 9 Wo2 cols 0-127, 10 Wo2 cols 128-255
// chunk flat=(c*4+kk)*64+lane holds 8 shorts: W^T[n=c*16+(lane&15)][k=kk*32+(lane>>4)*8 .. +8]
__global__ __launch_bounds__(256) void prepack_k(const float* __restrict__ W1,
                                                 const float* __restrict__ W2,
                                                 const float* __restrict__ Wo1,
                                                 const float* __restrict__ Wo2,
                                                 unsigned short* __restrict__ Wf) {
    int m = blockIdx.x;
    const float* W; int ld, col0;
    if (m < 4)       { W = W1 + m * 16384;      ld = 128; col0 = 0; }
    else if (m < 8)  { W = W2 + (m - 4) * 16384; ld = 128; col0 = 0; }
    else if (m == 8) { W = Wo1;                  ld = 128; col0 = 0; }
    else if (m == 9) { W = Wo2;                  ld = 256; col0 = 0; }
    else             { W = Wo2;                  ld = 256; col0 = 128; }
    unsigned short* dst = Wf + m * 16384;
    for (int flat = threadIdx.x; flat < 2048; flat += 256) {
        int c = flat >> 8, kk = (flat >> 6) & 3, lane = flat & 63;
        int n = col0 + c * 16 + (lane & 15);
        int k0 = kk * 32 + (lane >> 4) * 8;
        ushort4 lo, hi;
        lo.x = f2bf(W[(size_t)(k0 + 0) * ld + n]);
        lo.y = f2bf(W[(size_t)(k0 + 1) * ld + n]);
        lo.z = f2bf(W[(size_t)(k0 + 2) * ld + n]);
        lo.w = f2bf(W[(size_t)(k0 + 3) * ld + n]);
        hi.x = f2bf(W[(size_t)(k0 + 4) * ld + n]);
        hi.y = f2bf(W[(size_t)(k0 + 5) * ld + n]);
        hi.z = f2bf(W[(size_t)(k0 + 6) * ld + n]);
        hi.w = f2bf(W[(size_t)(k0 + 7) * ld + n]);
        *(ushort4*)&dst[flat * 8]     = lo;
        *(ushort4*)&dst[flat * 8 + 4] = hi;
    }
}

// ---------- CSR build: histogram -> exclusive scan -> fill ----------

__global__ __launch_bounds__(256) void hist_k(const int* __restrict__ ei,
                                              int* __restrict__ deg) {
    int e = blockIdx.x * 256 + threadIdx.x;
    if (e < NE) atomicAdd(&deg[ei[NE + e]], 1);
}

__global__ __launch_bounds__(256) void scan1_k(const int* __restrict__ deg,
                                               int* __restrict__ part,
                                               int* __restrict__ bsum) {
    __shared__ int ls[256];
    int tid = threadIdx.x;
    int base = blockIdx.x * 1024 + tid * 4;
    int v[4], s = 0;
#pragma unroll
    for (int j = 0; j < 4; j++) {
        int idx = base + j;
        v[j] = (idx < NN) ? deg[idx] : 0;
        s += v[j];
    }
    ls[tid] = s;
    __syncthreads();
    for (int off = 1; off < 256; off <<= 1) {
        int t2 = (tid >= off) ? ls[tid - off] : 0;
        __syncthreads();
        if (tid >= off) ls[tid] += t2;
        __syncthreads();
    }
    int run = ls[tid] - s;
#pragma unroll
    for (int j = 0; j < 4; j++) {
        int idx = base + j;
        if (idx < NOFF) part[idx] = run;
        run += v[j];
    }
    if (tid == 255) bsum[blockIdx.x] = ls[255];
}

__global__ __launch_bounds__(256) void scan2_k(int* __restrict__ bsum) {
    __shared__ int ls[256];
    int tid = threadIdx.x;
    int v = (tid < NBLK) ? bsum[tid] : 0;
    ls[tid] = v;
    __syncthreads();
    for (int off = 1; off < 256; off <<= 1) {
        int t2 = (tid >= off) ? ls[tid - off] : 0;
        __syncthreads();
        if (tid >= off) ls[tid] += t2;
        __syncthreads();
    }
    if (tid < NBLK) bsum[tid] = ls[tid] - v;
}

__global__ __launch_bounds__(256) void scan3_k(const int* __restrict__ part,
                                               const int* __restrict__ bsum,
                                               int* __restrict__ offsets,
                                               int* __restrict__ cursor) {
    int tid = threadIdx.x;
    int base = blockIdx.x * 1024 + tid * 4;
    int bs = bsum[blockIdx.x];
#pragma unroll
    for (int j = 0; j < 4; j++) {
        int idx = base + j;
        if (idx < NOFF) {
            int o = part[idx] + bs;
            offsets[idx] = o;
            if (idx < NN) cursor[idx] = o;
        }
    }
}

__global__ __launch_bounds__(256) void fill_k(const int* __restrict__ ei,
                                              int* __restrict__ cursor,
                                              int* __restrict__ adj) {
    int e = blockIdx.x * 256 + threadIdx.x;
    if (e < NE) {
        int p = atomicAdd(&cursor[ei[NE + e]], 1);
        if (p >= 0 && p < NE) adj[p] = ei[e];
    }
}

// ---------- gather: agg = bf16((1+eps)*h + sum_{j->i} h[j]), fp32 accum ----------
__global__ __launch_bounds__(256) void gather_k(const unsigned short* __restrict__ h,
                                                const int* __restrict__ offsets,
                                                const int* __restrict__ adj,
                                                const float* __restrict__ eps, int l,
                                                unsigned short* __restrict__ agg,
                                                float* __restrict__ stats_part) {
    if (blockIdx.x < NSPLIT) stats_part[blockIdx.x * 256 + threadIdx.x] = 0.f;
    int t = blockIdx.x * 256 + threadIdx.x;   // NN*32, 4 cols per thread
    int i = t >> 5, q = t & 31;
    const ushort4* hp = (const ushort4*)h;
    float e = 1.f + eps[l];
    ushort4 sv = hp[(size_t)i * 32 + q];
    float a0 = bf2f(sv.x) * e, a1 = bf2f(sv.y) * e, a2 = bf2f(sv.z) * e, a3 = bf2f(sv.w) * e;
    int s0 = offsets[i], s1 = offsets[i + 1];
    for (int k = s0; k < s1; k++) {
        int src = adj[k];
        ushort4 v = hp[(size_t)src * 32 + q];
        a0 += bf2f(v.x); a1 += bf2f(v.y); a2 += bf2f(v.z); a3 += bf2f(v.w);
    }
    ushort4 o;
    o.x = f2bf(a0); o.y = f2bf(a1); o.z = f2bf(a2); o.w = f2bf(a3);
    ((ushort4*)agg)[(size_t)i * 32 + q] = o;
}

// C[M,128] = op(bf16 A[M,128] @ Wf + bias); Wf prepacked fragment-order bf16.
// optional bf16 out, fused BN stats (wave-reduced over quads).
template <bool RELU, bool OBF16, bool STATS>
__global__ __launch_bounds__(256) void gemm128f(const unsigned short* __restrict__ A,
                                                const unsigned short* __restrict__ Wf,
                                                const float* __restrict__ bias,
                                                void* __restrict__ Cv, int ldC, int M,
                                                float* __restrict__ stats_part) {
    __shared__ short Wlds[16384];   // fragment-order: chunk flat=(c*4+kk)*64+lane
    __shared__ float sst[256];
    int tid = threadIdx.x;
    // stage 32 KB: lane-contiguous 16B copies (coalesced global, conflict-free LDS)
#pragma unroll
    for (int i = 0; i < 8; i++) {
        int flat = i * 256 + tid;
        ((bf16x8*)Wlds)[flat] = ((const bf16x8*)Wf)[flat];
    }
    if (STATS) sst[tid] = 0.f;
    __syncthreads();

    int w = tid >> 6, lane = tid & 63;
    int quad = lane >> 4, lr = lane & 15;
    int rowA = blockIdx.x * 64 + w * 16 + lr;
    bool rowOK = rowA < M;
    const unsigned short* ap = A + (size_t)rowA * 128 + quad * 8;

    f32x4 acc[8];
#pragma unroll
    for (int c = 0; c < 8; c++) acc[c] = (f32x4){0.f, 0.f, 0.f, 0.f};

#pragma unroll
    for (int kk = 0; kk < 4; kk++) {
        bf16x8 af = rowOK ? *(const bf16x8*)(ap + kk * 32)
                          : (bf16x8){0, 0, 0, 0, 0, 0, 0, 0};
#pragma unroll
        for (int c = 0; c < 8; c++) {
            bf16x8 bf = ((const bf16x8*)Wlds)[(c * 4 + kk) * 64 + lane];
            acc[c] = __builtin_amdgcn_mfma_f32_16x16x32_bf16(af, bf, acc[c], 0, 0, 0);
        }
    }

    int r0 = blockIdx.x * 64 + w * 16 + quad * 4;
#pragma unroll
    for (int c = 0; c < 8; c++) {
        int col = c * 16 + lr;
        float bv = bias[col];
        float ls = 0.f, ls2 = 0.f;
#pragma unroll
        for (int r = 0; r < 4; r++) {
            int row = r0 + r;
            if (row < M) {
                float v = acc[c][r] + bv;
                if (RELU) v = fmaxf(v, 0.f);
                if (OBF16)
                    ((unsigned short*)Cv)[(size_t)row * ldC + col] = f2bf(v);
                else
                    ((float*)Cv)[(size_t)row * ldC + col] = v;
                if (STATS) { ls += v; ls2 += v * v; }
            }
        }
        if (STATS) {
            // reduce across the 4 quads (lanes differing in bits 4,5) in-register
            ls  += __shfl_xor(ls, 16);  ls  += __shfl_xor(ls, 32);
            ls2 += __shfl_xor(ls2, 16); ls2 += __shfl_xor(ls2, 32);
            if (quad == 0) {
                atomicAdd(&sst[col], ls);
                atomicAdd(&sst[128 + col], ls2);
            }
        }
    }
    if (STATS) {
        __syncthreads();
        atomicAdd(&stats_part[(blockIdx.x & (NSPLIT - 1)) * 256 + tid], sst[tid]);
    }
}

// reduce stats_part -> coef[c]=gamma*istd, coef[128+c]=beta-mu*gamma*istd
__global__ __launch_bounds__(256) void finalize_stats_k(const float* __restrict__ stats_part,
                                                        const float* __restrict__ gamma,
                                                        const float* __restrict__ beta,
                                                        float* __restrict__ coef, float invN) {
    __shared__ float ls[256];
    int t = threadIdx.x;
    float s = 0.f;
    for (int p = 0; p < NSPLIT; p++) s += stats_part[p * 256 + t];
    ls[t] = s;
    __syncthreads();
    if (t < 128) {
        float mu = ls[t] * invN;
        float var = ls[128 + t] * invN - mu * mu;
        float a = gamma[t] * rsqrtf(var + 1e-5f);
        coef[t] = a;
        coef[128 + t] = beta[t] - mu * a;
    }
}

// h = bf16(relu(m*a + b) + h)
__global__ __launch_bounds__(256) void bn_apply_k(const float* __restrict__ m,
                                                  const float* __restrict__ coef,
                                                  unsigned short* __restrict__ h) {
    int t = blockIdx.x * 256 + threadIdx.x;   // NN*32, 4 cols per thread
    int c4 = t & 31;
    float4 a = ((const float4*)coef)[c4];
    float4 b = ((const float4*)coef)[32 + c4];
    float4 mv = ((const float4*)m)[t];
    ushort4 hv = ((const ushort4*)h)[t];
    float h0 = bf2f(hv.x) + fmaxf(mv.x * a.x + b.x, 0.f);
    float h1 = bf2f(hv.y) + fmaxf(mv.y * a.y + b.y, 0.f);
    float h2 = bf2f(hv.z) + fmaxf(mv.z * a.z + b.z, 0.f);
    float h3 = bf2f(hv.w) + fmaxf(mv.w * a.w + b.w, 0.f);
    ushort4 o;
    o.x = f2bf(h0); o.y = f2bf(h1); o.z = f2bf(h2); o.w = f2bf(h3);
    ((ushort4*)h)[t] = o;
}

// ---------- pooling (batch is sorted) ----------

__global__ __launch_bounds__(256) void gbound_k(const int* __restrict__ batch,
                                                int* __restrict__ gstart) {
    int i = blockIdx.x * 256 + threadIdx.x;
    if (i >= NN) return;
    int b = batch[i];
    int prev = (i == 0) ? -1 : batch[i - 1];
    for (int g = prev + 1; g <= b; g++) gstart[g] = i;
    if (i == NN - 1) {
        for (int g = b + 1; g <= NG; g++) gstart[g] = NN;
    }
}

// one block per graph: mean over its node rows -> bf16 pooled
__global__ __launch_bounds__(128) void pool_k(const unsigned short* __restrict__ h,
                                              const int* __restrict__ gstart,
                                              unsigned short* __restrict__ pooled) {
    int g = blockIdx.x, col = threadIdx.x;
    int r0 = gstart[g], r1 = gstart[g + 1];
    float s = 0.f;
    for (int r = r0; r < r1; r++) s += bf2f(h[(size_t)r * H + col]);
    pooled[(size_t)g * H + col] = f2bf(s / fmaxf((float)(r1 - r0), 1.f));
}

extern "C" void kernel_launch(void* const* d_in, const int* in_sizes, int n_in,
                              void* d_out, int out_size, void* d_ws, size_t ws_size,
                              hipStream_t stream) {
    const float* x     = (const float*)d_in[0];
    const int*   ei    = (const int*)d_in[1];
    const int*   batch = (const int*)d_in[2];
    const float* Wn    = (const float*)d_in[3];
    const float* bn_b  = (const float*)d_in[4];
    const float* eps   = (const float*)d_in[5];
    const float* W1    = (const float*)d_in[6];
    const float* b1    = (const float*)d_in[7];
    const float* W2    = (const float*)d_in[8];
    const float* b2    = (const float*)d_in[9];
    const float* gamma = (const float*)d_in[10];
    const float* beta  = (const float*)d_in[11];
    const float* Wo1   = (const float*)d_in[12];
    const float* bo1   = (const float*)d_in[13];
    const float* Wo2   = (const float*)d_in[14];
    const float* bo2   = (const float*)d_in[15];
    float* out = (float*)d_out;

    // ---- workspace: ~197 MB total ----
    unsigned short* h     = (unsigned short*)d_ws;                 // NN*H bf16
    float*          m     = (float*)(h + (size_t)NN * H);          // NN*H f32
    unsigned short* aggB  = (unsigned short*)(m + (size_t)NN * H); // NN*H bf16
    unsigned short* tB    = aggB + (size_t)NN * H;                 // NN*H bf16
    float* stats_part     = (float*)(tB + (size_t)NN * H);         // NSPLIT*256
    float* coef           = stats_part + NSPLIT * 256;             // 256
    unsigned short* Wf    = (unsigned short*)(coef + 256);         // 11*16384 bf16 (16B-aligned)
    unsigned short* pooledB = Wf + 11 * 16384;                     // NG*H bf16
    int* offsets = (int*)(pooledB + (size_t)NG * H);               // NOFF
    int* adj     = offsets + NOFF;                                 // NE
    int* gstart  = adj + NE;                                       // NG+1
    // transient CSR-build arrays overlaid in m (m is first written by layer-0
    // gemm2, strictly after the CSR build on the same stream)
    int* deg    = (int*)m;         // NN
    int* part   = deg + NN;        // NOFF
    int* bsum   = part + NOFF;     // 256
    int* cursor = bsum + 256;      // NN

    // weight prepack + CSR build (once; reused by all 4 layers)
    prepack_k<<<11, 256, 0, stream>>>(W1, W2, Wo1, Wo2, Wf);
    hipMemsetAsync(deg, 0, NN * sizeof(int), stream);
    hist_k<<<2344, 256, 0, stream>>>(ei, deg);
    scan1_k<<<NBLK, 256, 0, stream>>>(deg, part, bsum);
    scan2_k<<<1, 256, 0, stream>>>(bsum);
    scan3_k<<<NBLK, 256, 0, stream>>>(part, bsum, offsets, cursor);
    fill_k<<<2344, 256, 0, stream>>>(ei, cursor, adj);
    gbound_k<<<586, 256, 0, stream>>>(batch, gstart);

    encoder_k<<<75000, 256, 0, stream>>>(x, Wn, bn_b, h);

    for (int l = 0; l < 4; l++) {
        gather_k<<<18750, 256, 0, stream>>>(h, offsets, adj, eps, l, aggB, stats_part);
        gemm128f<true, true, false><<<2344, 256, 0, stream>>>(
            aggB, Wf + l * 16384, b1 + l * 128, tB, 128, NN, nullptr);
        gemm128f<false, false, true><<<2344, 256, 0, stream>>>(
            tB, Wf + (4 + l) * 16384, b2 + l * 128, m, 128, NN, stats_part);
        finalize_stats_k<<<1, 256, 0, stream>>>(stats_part, gamma + l * 128,
                                                beta + l * 128, coef, 1.f / NN);
        bn_apply_k<<<18750, 256, 0, stream>>>(m, coef, h);
    }

    pool_k<<<NG, 128, 0, stream>>>(h, gstart, pooledB);

    gemm128f<true, true, false><<<79, 256, 0, stream>>>(
        pooledB, Wf + 8 * 16384, bo1, tB, 128, NG, nullptr);
    gemm128f<false, false, false><<<79, 256, 0, stream>>>(
        tB, Wf + 9 * 16384, bo2, out, 256, NG, nullptr);
    gemm128f<false, false, false><<<79, 256, 0, stream>>>(
        tB, Wf + 10 * 16384, bo2 + 128, out + 128, 256, NG, nullptr);
}